// Round 1
// baseline (4335.252 us; speedup 1.0000x reference)
//
#include <hip/hip_runtime.h>
#include <math.h>

#define NTHREADS 256
#define HID 64
#define NLAYERS 8

__device__ __forceinline__ float relu_f(float v) { return v > 0.f ? v : 0.f; }

// One hidden->hidden matmul: h (regs) -> lds (per-thread column), then copy back.
// j-loop rolled (uniform weight rows -> s_load), k-loop unrolled (static reg idx).
__device__ __forceinline__ void mat_hh(const float* __restrict__ W,
                                       const float* __restrict__ B,
                                       float* __restrict__ h,
                                       float* __restrict__ lds, int tid) {
    for (int j = 0; j < HID; ++j) {
        const float* r = W + j * HID;
        float a0 = 0.f, a1 = 0.f, a2 = 0.f, a3 = 0.f;
#pragma unroll
        for (int k = 0; k < HID; k += 4) {
            a0 = fmaf(r[k + 0], h[k + 0], a0);
            a1 = fmaf(r[k + 1], h[k + 1], a1);
            a2 = fmaf(r[k + 2], h[k + 2], a2);
            a3 = fmaf(r[k + 3], h[k + 3], a3);
        }
        lds[j * NTHREADS + tid] = relu_f((a0 + a1) + (a2 + a3) + B[j]);
    }
#pragma unroll
    for (int k = 0; k < HID; ++k) h[k] = lds[k * NTHREADS + tid];
}

// Full 4-layer MLP for one net at coupling layer l; input is the single active
// scalar xa; returns the single passive output component.
__device__ __forceinline__ float mlp_eval(
    const float* __restrict__ w1, const float* __restrict__ b1,
    const float* __restrict__ w2, const float* __restrict__ b2,
    const float* __restrict__ w3, const float* __restrict__ b3,
    const float* __restrict__ w4, const float* __restrict__ b4,
    int l, int act, int pass, float xa,
    float* __restrict__ lds, int tid) {
    float h[HID];

    // layer 1: (2 -> 64), only column `act` of W1 matters (xm[pass] == 0)
    const float* W1 = w1 + l * HID * 2;
    const float* B1 = b1 + l * HID;
#pragma unroll
    for (int j = 0; j < HID; ++j)
        h[j] = relu_f(fmaf(W1[2 * j + act], xa, B1[j]));

    // layers 2,3: (64 -> 64)
    mat_hh(w2 + l * HID * HID, b2 + l * HID, h, lds, tid);
    mat_hh(w3 + l * HID * HID, b3 + l * HID, h, lds, tid);

    // layer 4: (64 -> 2), only row `pass` is consumed
    const float* W4 = w4 + l * 2 * HID + pass * HID;
    float a0 = 0.f, a1 = 0.f, a2 = 0.f, a3 = 0.f;
#pragma unroll
    for (int k = 0; k < HID; k += 4) {
        a0 = fmaf(W4[k + 0], h[k + 0], a0);
        a1 = fmaf(W4[k + 1], h[k + 1], a1);
        a2 = fmaf(W4[k + 2], h[k + 2], a2);
        a3 = fmaf(W4[k + 3], h[k + 3], a3);
    }
    return (a0 + a1) + (a2 + a3) + b4[l * 2 + pass];
}

__global__ __launch_bounds__(NTHREADS) void realnvp_kernel(
    const float* __restrict__ x,
    const float* __restrict__ s_w1, const float* __restrict__ s_b1,
    const float* __restrict__ s_w2, const float* __restrict__ s_b2,
    const float* __restrict__ s_w3, const float* __restrict__ s_b3,
    const float* __restrict__ s_w4, const float* __restrict__ s_b4,
    const float* __restrict__ t_w1, const float* __restrict__ t_b1,
    const float* __restrict__ t_w2, const float* __restrict__ t_b2,
    const float* __restrict__ t_w3, const float* __restrict__ t_b3,
    const float* __restrict__ t_w4, const float* __restrict__ t_b4,
    float* __restrict__ out, int n) {
    __shared__ float lds[HID * NTHREADS];  // 64 KB: per-thread activation column
    const int tid = threadIdx.x;
    const int i = blockIdx.x * NTHREADS + tid;
    if (i >= n) return;

    float2 xv = reinterpret_cast<const float2*>(x)[i];
    float y0 = xv.x, y1 = xv.y;
    float ld = 0.f;

    for (int l = 0; l < NLAYERS; ++l) {
        const int act = l & 1;        // even layer: mask [1,0] -> condition on comp 0
        const int pass = act ^ 1;
        const float xa = act ? y1 : y0;

        const float s_raw = mlp_eval(s_w1, s_b1, s_w2, s_b2, s_w3, s_b3,
                                     s_w4, s_b4, l, act, pass, xa, lds, tid);
        const float s = tanhf(s_raw);
        const float t = mlp_eval(t_w1, t_b1, t_w2, t_b2, t_w3, t_b3,
                                 t_w4, t_b4, l, act, pass, xa, lds, tid);

        const float yp_old = act ? y0 : y1;
        const float yp = fmaf(yp_old, __expf(s), t);
        if (act) y0 = yp; else y1 = yp;
        ld += s;
    }

    reinterpret_cast<float2*>(out)[i] = make_float2(y0, y1);
    out[2 * (size_t)n + i] = ld;
}

extern "C" void kernel_launch(void* const* d_in, const int* in_sizes, int n_in,
                              void* d_out, int out_size, void* d_ws, size_t ws_size,
                              hipStream_t stream) {
    const float* x = (const float*)d_in[0];
    const float* s_w1 = (const float*)d_in[1];
    const float* s_b1 = (const float*)d_in[2];
    const float* s_w2 = (const float*)d_in[3];
    const float* s_b2 = (const float*)d_in[4];
    const float* s_w3 = (const float*)d_in[5];
    const float* s_b3 = (const float*)d_in[6];
    const float* s_w4 = (const float*)d_in[7];
    const float* s_b4 = (const float*)d_in[8];
    const float* t_w1 = (const float*)d_in[9];
    const float* t_b1 = (const float*)d_in[10];
    const float* t_w2 = (const float*)d_in[11];
    const float* t_b2 = (const float*)d_in[12];
    const float* t_w3 = (const float*)d_in[13];
    const float* t_b3 = (const float*)d_in[14];
    const float* t_w4 = (const float*)d_in[15];
    const float* t_b4 = (const float*)d_in[16];

    const int n = in_sizes[0] / 2;  // x is (N, 2)
    const int blocks = (n + NTHREADS - 1) / NTHREADS;

    realnvp_kernel<<<blocks, NTHREADS, 0, stream>>>(
        x, s_w1, s_b1, s_w2, s_b2, s_w3, s_b3, s_w4, s_b4,
        t_w1, t_b1, t_w2, t_b2, t_w3, t_b3, t_w4, t_b4,
        (float*)d_out, n);
}

// Round 2
// 241.518 us; speedup vs baseline: 17.9500x; 17.9500x over previous
//
#include <hip/hip_runtime.h>
#include <hip/hip_bf16.h>
#include <math.h>

#define HID 64
#define NLAYERS 8
#define NTH 256
#define SF 4   // 16-sample fragments per wave => 64 samples/wave

typedef __attribute__((ext_vector_type(8))) short bf16x8;
typedef __attribute__((ext_vector_type(4))) float f32x4;

// ws layout (floats): [0,65536)  A-fragments as ushort[32][4096] (bf16)
//                     [65536, 65536+81920)  pack64 arrays float[16][5][1024]
//                     [147456, 147472)      b4 passive-component scalars
#define WS_P64_F 65536
#define WS_B4_F  (65536 + 81920)

__device__ __forceinline__ unsigned short f2bf(float f) {
    return __builtin_bit_cast(unsigned short, __float2bfloat16(f));
}

__device__ __forceinline__ bf16x8 packB(const f32x4 a, const f32x4 b) {
    bf16x8 o;
    o[0] = (short)f2bf(a[0]); o[1] = (short)f2bf(a[1]);
    o[2] = (short)f2bf(a[2]); o[3] = (short)f2bf(a[3]);
    o[4] = (short)f2bf(b[0]); o[5] = (short)f2bf(b[1]);
    o[6] = (short)f2bf(b[2]); o[7] = (short)f2bf(b[3]);
    return o;
}

// One block per (layer, net). Packs weights into MFMA fragment order with the
// K-axis permutation k_phys(ks,g,e) = 16*(2ks+(e>>2)) + 4g + (e&3), which makes
// the D-layout of layer n directly consumable as the B-operand of layer n+1.
__global__ void prepack_kernel(
    const float* __restrict__ s_w1, const float* __restrict__ s_b1,
    const float* __restrict__ s_w2, const float* __restrict__ s_b2,
    const float* __restrict__ s_w3, const float* __restrict__ s_b3,
    const float* __restrict__ s_w4, const float* __restrict__ s_b4,
    const float* __restrict__ t_w1, const float* __restrict__ t_b1,
    const float* __restrict__ t_w2, const float* __restrict__ t_b2,
    const float* __restrict__ t_w3, const float* __restrict__ t_b3,
    const float* __restrict__ t_w4, const float* __restrict__ t_b4,
    float* __restrict__ ws) {
    const int slot = blockIdx.x;            // l*2 + net
    const int l = slot >> 1, net = slot & 1;
    const int act = l & 1, pass = act ^ 1;
    const float* w1 = (net ? t_w1 : s_w1) + l * HID * 2;
    const float* b1 = (net ? t_b1 : s_b1) + l * HID;
    const float* w2 = (net ? t_w2 : s_w2) + l * HID * HID;
    const float* b2 = (net ? t_b2 : s_b2) + l * HID;
    const float* w3 = (net ? t_w3 : s_w3) + l * HID * HID;
    const float* b3 = (net ? t_b3 : s_b3) + l * HID;
    const float* w4 = (net ? t_w4 : s_w4) + l * 2 * HID;
    const float* b4 = (net ? t_b4 : s_b4) + l * 2;

    unsigned short* Aall = reinterpret_cast<unsigned short*>(ws);
    float* P64 = ws + WS_P64_F;
    float* B4P = ws + WS_B4_F;

    // A-operand fragments for the two 64x64 matmuls (W2, W3)
    for (int mat = 0; mat < 2; ++mat) {
        const float* W = mat ? w3 : w2;
        unsigned short* dst = Aall + (slot * 2 + mat) * 4096;
        for (int idx = threadIdx.x; idx < 4096; idx += NTH) {
            const int e = idx & 7, lane = (idx >> 3) & 63, fr = idx >> 9;
            const int ks = fr & 1, mf = fr >> 1;
            const int j = 16 * mf + (lane & 15);                       // out row
            const int k = 16 * (2 * ks + (e >> 2)) + 4 * (lane >> 4) + (e & 3);
            dst[idx] = f2bf(W[j * HID + k]);
        }
    }
    // pack64 arrays in D-layout order: dst[(f*64+lane)*4 + r] = v[16f + 4*(lane>>4) + r]
    for (int which = 0; which < 5; ++which) {
        float* dst = P64 + (slot * 5 + which) * 1024;
        for (int idx = threadIdx.x; idx < 1024; idx += NTH) {
            const int r = idx & 3, lane = (idx >> 2) & 63, f = idx >> 8;
            const int j = 16 * f + 4 * (lane >> 4) + r;
            float v;
            switch (which) {
                case 0:  v = w1[j * 2 + act];      break;   // active input column
                case 1:  v = b1[j];                break;
                case 2:  v = b2[j];                break;
                case 3:  v = b3[j];                break;
                default: v = w4[pass * HID + j];   break;   // passive output row
            }
            dst[idx] = v;
        }
    }
    if (threadIdx.x == 0) B4P[slot] = b4[pass];
}

__global__ __launch_bounds__(NTH) void nvp_mfma_kernel(
    const float* __restrict__ x, const float* __restrict__ ws,
    float* __restrict__ out, int n) {
    const int lane = threadIdx.x & 63;
    const int wid = (blockIdx.x * NTH + threadIdx.x) >> 6;
    const int c = lane & 15, g = lane >> 4;
    const int base = wid * (16 * SF);
    if (base >= n) return;

    const unsigned short* Aall = reinterpret_cast<const unsigned short*>(ws);
    const float* P64 = ws + WS_P64_F;
    const float* B4P = ws + WS_B4_F;

    float y0[SF], y1[SF], ldet[SF];
#pragma unroll
    for (int sf = 0; sf < SF; ++sf) {
        const float2 xv = reinterpret_cast<const float2*>(x)[base + 16 * sf + c];
        y0[sf] = xv.x; y1[sf] = xv.y; ldet[sf] = 0.f;
    }

    for (int l = 0; l < NLAYERS; ++l) {
        const int act = l & 1;
        float sv[SF], tv[SF];
#pragma unroll
        for (int net = 0; net < 2; ++net) {
            const int slot = l * 2 + net;
            const unsigned short* A2 = Aall + (slot * 2 + 0) * 4096;
            const unsigned short* A3 = Aall + (slot * 2 + 1) * 4096;
            const float* PB = P64 + slot * 5 * 1024;

            // ---- layer 1 (rank-1, VALU) straight into B-fragments ----
            bf16x8 bfr[SF][2];
            {
                f32x4 w1v[4], b1v[4];
#pragma unroll
                for (int f = 0; f < 4; ++f) {
                    w1v[f] = *reinterpret_cast<const f32x4*>(PB + 0 * 1024 + (f * 64 + lane) * 4);
                    b1v[f] = *reinterpret_cast<const f32x4*>(PB + 1 * 1024 + (f * 64 + lane) * 4);
                }
#pragma unroll
                for (int sf = 0; sf < SF; ++sf) {
                    const float xa = act ? y1[sf] : y0[sf];
                    f32x4 v[4];
#pragma unroll
                    for (int f = 0; f < 4; ++f)
#pragma unroll
                        for (int r = 0; r < 4; ++r)
                            v[f][r] = fmaxf(fmaf(w1v[f][r], xa, b1v[f][r]), 0.f);
                    bfr[sf][0] = packB(v[0], v[1]);
                    bfr[sf][1] = packB(v[2], v[3]);
                }
            }

            f32x4 acc[SF][4];
            // ---- layer 2: 64x64 MFMA, bias as C-in ----
#pragma unroll
            for (int mf = 0; mf < 4; ++mf) {
                const bf16x8 a0 = *reinterpret_cast<const bf16x8*>(A2 + ((mf * 2 + 0) * 64 + lane) * 8);
                const bf16x8 a1 = *reinterpret_cast<const bf16x8*>(A2 + ((mf * 2 + 1) * 64 + lane) * 8);
                const f32x4 bias = *reinterpret_cast<const f32x4*>(PB + 2 * 1024 + (mf * 64 + lane) * 4);
#pragma unroll
                for (int sf = 0; sf < SF; ++sf) {
                    f32x4 t0 = __builtin_amdgcn_mfma_f32_16x16x32_bf16(a0, bfr[sf][0], bias, 0, 0, 0);
                    acc[sf][mf] = __builtin_amdgcn_mfma_f32_16x16x32_bf16(a1, bfr[sf][1], t0, 0, 0, 0);
                }
            }
            // relu + repack (identity layout: no cross-lane movement)
#pragma unroll
            for (int sf = 0; sf < SF; ++sf) {
#pragma unroll
                for (int mf = 0; mf < 4; ++mf)
#pragma unroll
                    for (int r = 0; r < 4; ++r)
                        acc[sf][mf][r] = fmaxf(acc[sf][mf][r], 0.f);
                bfr[sf][0] = packB(acc[sf][0], acc[sf][1]);
                bfr[sf][1] = packB(acc[sf][2], acc[sf][3]);
            }
            // ---- layer 3: 64x64 MFMA ----
#pragma unroll
            for (int mf = 0; mf < 4; ++mf) {
                const bf16x8 a0 = *reinterpret_cast<const bf16x8*>(A3 + ((mf * 2 + 0) * 64 + lane) * 8);
                const bf16x8 a1 = *reinterpret_cast<const bf16x8*>(A3 + ((mf * 2 + 1) * 64 + lane) * 8);
                const f32x4 bias = *reinterpret_cast<const f32x4*>(PB + 3 * 1024 + (mf * 64 + lane) * 4);
#pragma unroll
                for (int sf = 0; sf < SF; ++sf) {
                    f32x4 t0 = __builtin_amdgcn_mfma_f32_16x16x32_bf16(a0, bfr[sf][0], bias, 0, 0, 0);
                    acc[sf][mf] = __builtin_amdgcn_mfma_f32_16x16x32_bf16(a1, bfr[sf][1], t0, 0, 0, 0);
                }
            }
            // ---- layer 4: single passive-row dot (VALU) + cross-group reduce ----
            const float b4v = B4P[slot];
            f32x4 w4v[4];
#pragma unroll
            for (int f = 0; f < 4; ++f)
                w4v[f] = *reinterpret_cast<const f32x4*>(PB + 4 * 1024 + (f * 64 + lane) * 4);
#pragma unroll
            for (int sf = 0; sf < SF; ++sf) {
                float p0 = 0.f, p1 = 0.f;
#pragma unroll
                for (int f = 0; f < 4; ++f) {
                    p0 = fmaf(w4v[f][0], fmaxf(acc[sf][f][0], 0.f), p0);
                    p1 = fmaf(w4v[f][1], fmaxf(acc[sf][f][1], 0.f), p1);
                    p0 = fmaf(w4v[f][2], fmaxf(acc[sf][f][2], 0.f), p0);
                    p1 = fmaf(w4v[f][3], fmaxf(acc[sf][f][3], 0.f), p1);
                }
                float p = p0 + p1;
                p += __shfl_xor(p, 16, 64);   // reduce across the 4 lane-groups
                p += __shfl_xor(p, 32, 64);
                p += b4v;
                if (net == 0) sv[sf] = p; else tv[sf] = p;
            }
        }
        // ---- coupling update ----
#pragma unroll
        for (int sf = 0; sf < SF; ++sf) {
            const float e2 = __expf(2.f * sv[sf]);
            const float s = 1.f - 2.f / (e2 + 1.f);      // tanh(sv)
            const float es = __expf(s);
            if (act) y0[sf] = fmaf(y0[sf], es, tv[sf]);
            else     y1[sf] = fmaf(y1[sf], es, tv[sf]);
            ldet[sf] += s;
        }
    }

    if (g == 0) {   // 4 lane-groups hold identical results; group 0 writes
#pragma unroll
        for (int sf = 0; sf < SF; ++sf) {
            const int sid = base + 16 * sf + c;
            reinterpret_cast<float2*>(out)[sid] = make_float2(y0[sf], y1[sf]);
            out[2 * (size_t)n + sid] = ldet[sf];
        }
    }
}

extern "C" void kernel_launch(void* const* d_in, const int* in_sizes, int n_in,
                              void* d_out, int out_size, void* d_ws, size_t ws_size,
                              hipStream_t stream) {
    const float* x = (const float*)d_in[0];
    float* ws = (float*)d_ws;

    prepack_kernel<<<16, NTH, 0, stream>>>(
        (const float*)d_in[1],  (const float*)d_in[2],  (const float*)d_in[3],
        (const float*)d_in[4],  (const float*)d_in[5],  (const float*)d_in[6],
        (const float*)d_in[7],  (const float*)d_in[8],  (const float*)d_in[9],
        (const float*)d_in[10], (const float*)d_in[11], (const float*)d_in[12],
        (const float*)d_in[13], (const float*)d_in[14], (const float*)d_in[15],
        (const float*)d_in[16], ws);

    const int n = in_sizes[0] / 2;                 // x is (N, 2)
    const int samples_per_block = (NTH / 64) * 16 * SF;   // 256
    const int blocks = (n + samples_per_block - 1) / samples_per_block;

    nvp_mfma_kernel<<<blocks, NTH, 0, stream>>>(x, ws, (float*)d_out, n);
}

// Round 3
// 230.119 us; speedup vs baseline: 18.8392x; 1.0495x over previous
//
#include <hip/hip_runtime.h>
#include <hip/hip_bf16.h>
#include <math.h>

#define HID 64
#define NLAYERS 8
#define NTH 256
#define SF 8   // 16-sample fragments per wave => 128 samples/wave

typedef __attribute__((ext_vector_type(8))) short bf16x8;
typedef __attribute__((ext_vector_type(8))) __bf16 bf16v8;
typedef __attribute__((ext_vector_type(4))) float f32x4;

// ws layout (floats): [0,65536)            A2/A3 fragments ushort[32][4096]
//                     [65536,65536+81920)  P64: per slot 5 regions of 1024 floats
//                        which==0: A1 frags as ushort[2048] (mf=0..3, ks=0)
//                        which==1: b1 bias in D-frag order (f32)
//                        which==2: b2 bias (f32)   which==3: b3 bias (f32)
//                        which==4: A4 frags as ushort[1024] (ks=0,1), rest unused
//                     [147456,147472)      b4 passive-component scalars
#define WS_P64_F 65536
#define WS_B4_F  (65536 + 81920)

__device__ __forceinline__ unsigned short f2bf(float f) {
    return __builtin_bit_cast(unsigned short, (__bf16)f);
}

// relu + f32->bf16 pack; native __bf16 casts fuse into v_cvt_pk_bf16_f32
__device__ __forceinline__ bf16x8 packR(f32x4 a, f32x4 b) {
    bf16v8 t;
    t[0] = (__bf16)fmaxf(a[0], 0.f);
    t[1] = (__bf16)fmaxf(a[1], 0.f);
    t[2] = (__bf16)fmaxf(a[2], 0.f);
    t[3] = (__bf16)fmaxf(a[3], 0.f);
    t[4] = (__bf16)fmaxf(b[0], 0.f);
    t[5] = (__bf16)fmaxf(b[1], 0.f);
    t[6] = (__bf16)fmaxf(b[2], 0.f);
    t[7] = (__bf16)fmaxf(b[3], 0.f);
    return __builtin_bit_cast(bf16x8, t);
}

// One block per (layer, net). A-frag K-permutation k(ks,g,e)=16*(2ks+(e>>2))+4g+(e&3)
// makes layer n's D-layout directly consumable as layer n+1's B-operand.
__global__ void prepack_kernel(
    const float* __restrict__ s_w1, const float* __restrict__ s_b1,
    const float* __restrict__ s_w2, const float* __restrict__ s_b2,
    const float* __restrict__ s_w3, const float* __restrict__ s_b3,
    const float* __restrict__ s_w4, const float* __restrict__ s_b4,
    const float* __restrict__ t_w1, const float* __restrict__ t_b1,
    const float* __restrict__ t_w2, const float* __restrict__ t_b2,
    const float* __restrict__ t_w3, const float* __restrict__ t_b3,
    const float* __restrict__ t_w4, const float* __restrict__ t_b4,
    float* __restrict__ ws) {
    const int slot = blockIdx.x;            // l*2 + net
    const int l = slot >> 1, net = slot & 1;
    const int act = l & 1, pass = act ^ 1;
    const float* w1 = (net ? t_w1 : s_w1) + l * HID * 2;
    const float* b1 = (net ? t_b1 : s_b1) + l * HID;
    const float* w2 = (net ? t_w2 : s_w2) + l * HID * HID;
    const float* b2 = (net ? t_b2 : s_b2) + l * HID;
    const float* w3 = (net ? t_w3 : s_w3) + l * HID * HID;
    const float* b3 = (net ? t_b3 : s_b3) + l * HID;
    const float* w4 = (net ? t_w4 : s_w4) + l * 2 * HID;
    const float* b4 = (net ? t_b4 : s_b4) + l * 2;

    unsigned short* Aall = reinterpret_cast<unsigned short*>(ws);
    float* P64 = ws + WS_P64_F;
    float* B4P = ws + WS_B4_F;

    // A-operand fragments for the two 64x64 matmuls (W2, W3)
    for (int mat = 0; mat < 2; ++mat) {
        const float* W = mat ? w3 : w2;
        unsigned short* dst = Aall + (slot * 2 + mat) * 4096;
        for (int idx = threadIdx.x; idx < 4096; idx += NTH) {
            const int e = idx & 7, lane = (idx >> 3) & 63, fr = idx >> 9;
            const int ks = fr & 1, mf = fr >> 1;
            const int j = 16 * mf + (lane & 15);                       // out row
            const int k = 16 * (2 * ks + (e >> 2)) + 4 * (lane >> 4) + (e & 3);
            dst[idx] = f2bf(W[j * HID + k]);
        }
    }
    // which==0: A1 fragments (rank-1 layer 1; only k_phys==0 is nonzero -> ks=0, e=0, g=0)
    {
        unsigned short* dst = reinterpret_cast<unsigned short*>(P64 + (slot * 5 + 0) * 1024);
        for (int idx = threadIdx.x; idx < 2048; idx += NTH) {
            const int e = idx & 7, lane = (idx >> 3) & 63, mf = idx >> 9;
            const int j = 16 * mf + (lane & 15);
            const float v = (e == 0 && (lane >> 4) == 0) ? w1[2 * j + act] : 0.f;
            dst[idx] = f2bf(v);
        }
    }
    // which==1..3: bias fragments in D-layout order (f32)
    for (int which = 1; which <= 3; ++which) {
        float* dst = P64 + (slot * 5 + which) * 1024;
        const float* B = (which == 1) ? b1 : (which == 2) ? b2 : b3;
        for (int idx = threadIdx.x; idx < 1024; idx += NTH) {
            const int r = idx & 3, lane = (idx >> 2) & 63, f = idx >> 8;
            const int j = 16 * f + 4 * (lane >> 4) + r;
            dst[idx] = B[j];
        }
    }
    // which==4: A4 fragments (W4 passive row in A row 0, rows 1..15 zero)
    {
        unsigned short* dst = reinterpret_cast<unsigned short*>(P64 + (slot * 5 + 4) * 1024);
        for (int idx = threadIdx.x; idx < 1024; idx += NTH) {
            const int e = idx & 7, lane = (idx >> 3) & 63, ks = idx >> 9;
            const int k = 16 * (2 * ks + (e >> 2)) + 4 * (lane >> 4) + (e & 3);
            const float v = ((lane & 15) == 0) ? w4[pass * HID + k] : 0.f;
            dst[idx] = f2bf(v);
        }
    }
    if (threadIdx.x == 0) B4P[slot] = b4[pass];
}

__global__ __launch_bounds__(NTH) void nvp_mfma_kernel(
    const float* __restrict__ x, const float* __restrict__ ws,
    float* __restrict__ out, int n) {
    const int lane = threadIdx.x & 63;
    const int wid = (blockIdx.x * NTH + threadIdx.x) >> 6;
    const int c = lane & 15, g = lane >> 4;
    const long base = (long)wid * (16 * SF);
    if (base >= n) return;

    const unsigned short* Aall = reinterpret_cast<const unsigned short*>(ws);
    const float* P64 = ws + WS_P64_F;
    const float* B4P = ws + WS_B4_F;

    float y0[SF], y1[SF], ld[SF];
#pragma unroll
    for (int sf = 0; sf < SF; ++sf) {
        const float2 xv = reinterpret_cast<const float2*>(x)[base + 16 * sf + c];
        y0[sf] = xv.x; y1[sf] = xv.y; ld[sf] = 0.f;
    }

    for (int l = 0; l < NLAYERS; ++l) {
        const int act = l & 1;
        float sv[SF], tv[SF];
#pragma unroll
        for (int net = 0; net < 2; ++net) {
            const int slot = l * 2 + net;
            const float* PB = P64 + slot * 5 * 1024;
            const unsigned short* A1p = reinterpret_cast<const unsigned short*>(PB);
            const unsigned short* A4p = reinterpret_cast<const unsigned short*>(PB + 4 * 1024);
            const unsigned short* A2 = Aall + (slot * 2 + 0) * 4096;
            const unsigned short* A3 = Aall + (slot * 2 + 1) * 4096;

            // ---- phase A weights: A1, b1, A2, b2 (held in registers) ----
            bf16x8 a1[4], a2[8];
            f32x4 c1[4], c2[4];
#pragma unroll
            for (int mf = 0; mf < 4; ++mf) {
                a1[mf] = *reinterpret_cast<const bf16x8*>(A1p + (mf * 64 + lane) * 8);
                c1[mf] = *reinterpret_cast<const f32x4*>(PB + 1 * 1024 + (mf * 64 + lane) * 4);
                c2[mf] = *reinterpret_cast<const f32x4*>(PB + 2 * 1024 + (mf * 64 + lane) * 4);
            }
#pragma unroll
            for (int fr = 0; fr < 8; ++fr)
                a2[fr] = *reinterpret_cast<const bf16x8*>(A2 + (fr * 64 + lane) * 8);

            bf16x8 bfr[SF][2];
#pragma unroll
            for (int sf = 0; sf < SF; ++sf) {
                const float xa = act ? y1[sf] : y0[sf];
                // B1 frag: bf16(xa) at k_phys==0 (element 0, lanes g==0), zeros elsewhere
                bf16x8 b1f = (bf16x8)0;
                b1f[0] = (g == 0) ? (short)f2bf(xa) : (short)0;
                f32x4 acc[4];
                // layer 1: rank-1 MFMA, bias as C-in (K slots 1..31 of A are zero)
#pragma unroll
                for (int mf = 0; mf < 4; ++mf)
                    acc[mf] = __builtin_amdgcn_mfma_f32_16x16x32_bf16(a1[mf], b1f, c1[mf], 0, 0, 0);
                bf16x8 bb0 = packR(acc[0], acc[1]);
                bf16x8 bb1 = packR(acc[2], acc[3]);
                // layer 2
#pragma unroll
                for (int mf = 0; mf < 4; ++mf) {
                    f32x4 t0 = __builtin_amdgcn_mfma_f32_16x16x32_bf16(a2[2 * mf + 0], bb0, c2[mf], 0, 0, 0);
                    acc[mf]  = __builtin_amdgcn_mfma_f32_16x16x32_bf16(a2[2 * mf + 1], bb1, t0, 0, 0, 0);
                }
                bfr[sf][0] = packR(acc[0], acc[1]);
                bfr[sf][1] = packR(acc[2], acc[3]);
            }

            // ---- phase B weights: A3, b3, A4, b4 ----
            bf16x8 a3[8], a4[2];
            f32x4 c3[4];
#pragma unroll
            for (int fr = 0; fr < 8; ++fr)
                a3[fr] = *reinterpret_cast<const bf16x8*>(A3 + (fr * 64 + lane) * 8);
#pragma unroll
            for (int mf = 0; mf < 4; ++mf)
                c3[mf] = *reinterpret_cast<const f32x4*>(PB + 3 * 1024 + (mf * 64 + lane) * 4);
            a4[0] = *reinterpret_cast<const bf16x8*>(A4p + (0 * 64 + lane) * 8);
            a4[1] = *reinterpret_cast<const bf16x8*>(A4p + (1 * 64 + lane) * 8);
            const float b4v = B4P[slot];

#pragma unroll
            for (int sf = 0; sf < SF; ++sf) {
                f32x4 acc[4];
                // layer 3
#pragma unroll
                for (int mf = 0; mf < 4; ++mf) {
                    f32x4 t0 = __builtin_amdgcn_mfma_f32_16x16x32_bf16(a3[2 * mf + 0], bfr[sf][0], c3[mf], 0, 0, 0);
                    acc[mf]  = __builtin_amdgcn_mfma_f32_16x16x32_bf16(a3[2 * mf + 1], bfr[sf][1], t0, 0, 0, 0);
                }
                bf16x8 bb0 = packR(acc[0], acc[1]);
                bf16x8 bb1 = packR(acc[2], acc[3]);
                // layer 4: W4 row dot via MFMA row 0, then broadcast from lane c
                f32x4 z = {0.f, 0.f, 0.f, 0.f};
                f32x4 d4 = __builtin_amdgcn_mfma_f32_16x16x32_bf16(a4[0], bb0, z, 0, 0, 0);
                d4 = __builtin_amdgcn_mfma_f32_16x16x32_bf16(a4[1], bb1, d4, 0, 0, 0);
                float p = __builtin_bit_cast(float,
                            __builtin_amdgcn_ds_bpermute(c * 4, __builtin_bit_cast(int, d4[0])));
                p += b4v;
                if (net == 0) sv[sf] = p; else tv[sf] = p;
            }
        }
        // ---- coupling update ----
#pragma unroll
        for (int sf = 0; sf < SF; ++sf) {
            const float e2 = __expf(2.f * sv[sf]);
            const float s = 1.f - 2.f / (e2 + 1.f);      // tanh(sv)
            const float es = __expf(s);
            if (act) y0[sf] = fmaf(y0[sf], es, tv[sf]);
            else     y1[sf] = fmaf(y1[sf], es, tv[sf]);
            ld[sf] += s;
        }
    }

    if (g == 0) {   // 4 lane-groups hold identical results; group 0 writes
#pragma unroll
        for (int sf = 0; sf < SF; ++sf) {
            const long sid = base + 16 * sf + c;
            reinterpret_cast<float2*>(out)[sid] = make_float2(y0[sf], y1[sf]);
            out[2 * (long)n + sid] = ld[sf];
        }
    }
}

extern "C" void kernel_launch(void* const* d_in, const int* in_sizes, int n_in,
                              void* d_out, int out_size, void* d_ws, size_t ws_size,
                              hipStream_t stream) {
    const float* x = (const float*)d_in[0];
    float* ws = (float*)d_ws;

    prepack_kernel<<<16, NTH, 0, stream>>>(
        (const float*)d_in[1],  (const float*)d_in[2],  (const float*)d_in[3],
        (const float*)d_in[4],  (const float*)d_in[5],  (const float*)d_in[6],
        (const float*)d_in[7],  (const float*)d_in[8],  (const float*)d_in[9],
        (const float*)d_in[10], (const float*)d_in[11], (const float*)d_in[12],
        (const float*)d_in[13], (const float*)d_in[14], (const float*)d_in[15],
        (const float*)d_in[16], ws);

    const int n = in_sizes[0] / 2;                        // x is (N, 2)
    const int samples_per_block = (NTH / 64) * 16 * SF;   // 512
    const int blocks = (n + samples_per_block - 1) / samples_per_block;

    nvp_mfma_kernel<<<blocks, NTH, 0, stream>>>(x, ws, (float*)d_out, n);
}